// Round 6
// baseline (345.540 us; speedup 1.0000x reference)
//
#include <hip/hip_runtime.h>

#define N_NODES 100000
#define N_EDGES 1600000
#define NPB 32                       // nodes per bucket (dst >> 5)
#define NB (N_NODES / NPB)           // 3125 buckets
#define CAP 704                      // slots per bucket (mean 512 + 8.5 sigma)
#define NCC 49                       // coarse cells (dst >> 11)
#define CAPA 34816                   // slots per coarse cell (mean 32768 + 11 sigma)
#define NFB 64                       // fine buckets per coarse cell
#define BPC 16                       // blocks per cell in pass B
#define N16 (N_NODES * 16)           // elements per half-table (16 cols/node)
#define GHB 6250                     // node-blocks per half-pass (6250*16 = 100000)
#define M1W 50000                    // mask1 u64 words (N*32/64)
#define M2W 100000                   // mask2 u64 words (N*64/64)

typedef float v2f __attribute__((ext_vector_type(2)));

// ---------------- JAX threefry2x32 (partitionable scheme) ----------------
struct U2 { unsigned a, b; };

__host__ __device__ constexpr U2 tf2x32(unsigned k0, unsigned k1, unsigned c0, unsigned c1) {
  unsigned ks2 = k0 ^ k1 ^ 0x1BD11BDAu;
  unsigned x0 = c0 + k0, x1 = c1 + k1;
#define TFR(r) { x0 += x1; x1 = (x1 << (r)) | (x1 >> (32 - (r))); x1 ^= x0; }
  TFR(13) TFR(15) TFR(26) TFR(6)
  x0 += k1;  x1 += ks2 + 1u;
  TFR(17) TFR(29) TFR(16) TFR(24)
  x0 += ks2; x1 += k0 + 2u;
  TFR(13) TFR(15) TFR(26) TFR(6)
  x0 += k0;  x1 += k1 + 3u;
  TFR(17) TFR(29) TFR(16) TFR(24)
  x0 += k1;  x1 += ks2 + 4u;
  TFR(13) TFR(15) TFR(26) TFR(6)
  x0 += ks2; x1 += k0 + 5u;
#undef TFR
  return U2{x0, x1};
}

constexpr U2 DK0 = tf2x32(0u, 42u, 0u, 0u);
constexpr U2 DK1 = tf2x32(0u, 42u, 0u, 1u);

__device__ __forceinline__ bool keep_bit(unsigned k0, unsigned k1, unsigned j) {
  U2 w = tf2x32(k0, k1, 0u, j);
  return ((w.a ^ w.b) >> 31) == 0u;
}

// bf16 storage helpers (RNE pack, shift unpack)
__device__ __forceinline__ unsigned short f2bf(float f) {
  unsigned u = __float_as_uint(f);
  u += 0x7FFFu + ((u >> 16) & 1u);
  return (unsigned short)(u >> 16);
}
// unpack uint32 (2 bf16) -> v2f
__device__ __forceinline__ v2f up2(unsigned r) {
  v2f v;
  v.x = __uint_as_float(r << 16);
  v.y = __uint_as_float(r & 0xFFFF0000u);
  return v;
}

// ------ Mask precompute + weight transposes -------------------------------
// Masks are pure functions of constants; blocks 0..3 also write transposed
// weight tables (col-major, 32 KB) so the per-thread GEMM kernels read
// weights via wave-uniform scalar loads (SMEM path; round-5 SGPR=112
// confirmed the s_load path materializes).
__global__ __launch_bounds__(256) void k_mask(
    unsigned long long* __restrict__ msk,
    const float* __restrict__ W1l, const float* __restrict__ W1r,
    const float* __restrict__ W2l, const float* __restrict__ W2r,
    float* __restrict__ wt) {
  int bid = blockIdx.x, tid = threadIdx.x;
  if (bid == 0) {
    for (int i = tid; i < 2048; i += 256) { int c = i >> 6, k = i & 63; wt[i] = W1l[k * 32 + c]; }
  } else if (bid == 1) {
    for (int i = tid; i < 2048; i += 256) { int c = i >> 6, k = i & 63; wt[2048 + i] = W1r[k * 32 + c]; }
  } else if (bid == 2) {
    for (int i = tid; i < 2048; i += 256) { int c = i >> 5, k = i & 31; wt[4096 + i] = W2l[k * 64 + c]; }
  } else if (bid == 3) {
    for (int i = tid; i < 2048; i += 256) { int c = i >> 5, k = i & 31; wt[6144 + i] = W2r[k * 64 + c]; }
  }
  int w = (int)((blockIdx.x * blockDim.x + threadIdx.x) >> 6);
  int lane = threadIdx.x & 63;
  int nw = (int)((gridDim.x * blockDim.x) >> 6);
  for (; w < M1W + M2W; w += nw) {
    unsigned k0, k1, j;
    if (w < M1W) { k0 = DK0.a; k1 = DK0.b; j = (unsigned)w * 64u + (unsigned)lane; }
    else { k0 = DK1.a; k1 = DK1.b; j = (unsigned)(w - M1W) * 64u + (unsigned)lane; }
    unsigned long long bits = __ballot(keep_bit(k0, k1, j));
    if (lane == 0) msk[w] = bits;
  }
}

// ------ Kernel A: one THREAD per node, spill-free ------------------------
// Only xv[64] stays live across the column loops. Left cols computed in
// bf16 pairs packed on the fly (pk[16]); right cols in float4 groups stored
// immediately. Weights via uniform s_load from transposed tables.
// launch_bounds(256,3) caps VGPR at 170 so the allocator never spills
// (round-5 failure: 130 live floats vs 100 allocated -> scratch).
__global__ __launch_bounds__(256, 3) void k_transform1(
    const float* __restrict__ x, const float* __restrict__ W1lT,
    const float* __restrict__ W1rT, unsigned short* __restrict__ xlbh,
    float* __restrict__ xr) {
  int node = blockIdx.x * 256 + threadIdx.x;
  if (node >= N_NODES) return;
  float xv[64];
  const float4* xp = (const float4*)(x + (size_t)node * 64);
#pragma unroll
  for (int i = 0; i < 16; ++i) ((float4*)xv)[i] = xp[i];
  // left matrix: bf16 pairs, packed as computed (no xl[32] array)
  unsigned pk[16];
#pragma unroll 8
  for (int c2 = 0; c2 < 16; ++c2) {
    const float* w0 = W1lT + (2 * c2) * 64;
    const float* w1 = W1lT + (2 * c2 + 1) * 64;
    float a0 = 0.f, a1 = 0.f;
#pragma unroll
    for (int k = 0; k < 64; ++k) { a0 += xv[k] * w0[k]; a1 += xv[k] * w1[k]; }
    pk[c2] = (unsigned)f2bf(a0) | ((unsigned)f2bf(a1) << 16);
  }
  uint4* o0 = (uint4*)(xlbh + (size_t)node * 16);
  uint4* o1 = (uint4*)(xlbh + (size_t)N16 + (size_t)node * 16);
  o0[0] = make_uint4(pk[0], pk[1], pk[2], pk[3]);
  o0[1] = make_uint4(pk[4], pk[5], pk[6], pk[7]);
  o1[0] = make_uint4(pk[8], pk[9], pk[10], pk[11]);
  o1[1] = make_uint4(pk[12], pk[13], pk[14], pk[15]);
  // right matrix: float4 per 4 cols, stored immediately (no xro[32] array)
  float4* xo = (float4*)(xr + (size_t)node * 32);
#pragma unroll 4
  for (int c4 = 0; c4 < 8; ++c4) {
    float r0 = 0.f, r1 = 0.f, r2 = 0.f, r3 = 0.f;
    const float* w0 = W1rT + (c4 * 4 + 0) * 64;
    const float* w1 = W1rT + (c4 * 4 + 1) * 64;
    const float* w2 = W1rT + (c4 * 4 + 2) * 64;
    const float* w3 = W1rT + (c4 * 4 + 3) * 64;
#pragma unroll
    for (int k = 0; k < 64; ++k) {
      r0 += xv[k] * w0[k]; r1 += xv[k] * w1[k];
      r2 += xv[k] * w2[k]; r3 += xv[k] * w3[k];
    }
    xo[c4] = make_float4(r0, r1, r2, r3);
  }
}

// ------ Pass A: LDS-staged partition by coarse cell (dst>>11), 49 cells ---
__global__ __launch_bounds__(256) void k_binA(
    const int* __restrict__ src, const int* __restrict__ dst,
    int* __restrict__ curA, unsigned* __restrict__ bufA) {
  __shared__ int hist[NCC];
  __shared__ int offsL[NCC + 1];
  __shared__ int baseL[NCC];
  __shared__ int place[NCC];
  __shared__ unsigned stag[2048];
  __shared__ unsigned char cellb[2048];
  int t = threadIdx.x;
  for (long long start = (long long)blockIdx.x * 2048; start < N_EDGES;
       start += (long long)gridDim.x * 2048) {
    int n = (int)min((long long)2048, (long long)N_EDGES - start);
    for (int i = t; i < NCC; i += 256) hist[i] = 0;
    __syncthreads();
    unsigned pv[8]; int pc[8];
#pragma unroll
    for (int i = 0; i < 8; ++i) {
      int idx = t + i * 256;
      if (idx < n) {
        int d = dst[start + idx];
        int s = src[start + idx];
        int cc = d >> 11;
        pc[i] = cc;
        pv[i] = (unsigned)s | ((unsigned)(d & 2047) << 17);
        atomicAdd(&hist[cc], 1);
      } else pc[i] = -1;
    }
    __syncthreads();
    if (t < 64) {
      int lane = t;
      int v = (lane < NCC) ? hist[lane] : 0;
      int x = v;
#pragma unroll
      for (int o = 1; o < 64; o <<= 1) {
        int y = __shfl_up(x, o, 64);
        if (lane >= o) x += y;
      }
      if (lane < NCC) {
        offsL[lane] = x - v;
        place[lane] = 0;
        if (v > 0) baseL[lane] = atomicAdd(&curA[lane], v);
      }
      if (lane == NCC - 1) offsL[NCC] = x;
    }
    __syncthreads();
#pragma unroll
    for (int i = 0; i < 8; ++i) {
      if (pc[i] >= 0) {
        int p = atomicAdd(&place[pc[i]], 1);
        int sl = offsL[pc[i]] + p;
        stag[sl] = pv[i];
        cellb[sl] = (unsigned char)pc[i];
      }
    }
    __syncthreads();
    for (int s2 = t; s2 < n; s2 += 256) {     // coalesced copy-out, no search
      int cell = cellb[s2];
      int pos = baseL[cell] + (s2 - offsL[cell]);
      if (pos < CAPA) bufA[(size_t)cell * CAPA + pos] = stag[s2];
    }
    __syncthreads();
  }
}

// ------ Pass B: refine each coarse cell into 64 fine buckets -------------
__global__ __launch_bounds__(256) void k_binB(
    const unsigned* __restrict__ bufA, const int* __restrict__ curA,
    int* __restrict__ cur, unsigned* __restrict__ buf) {
  __shared__ int hist[NFB];
  __shared__ int offsL[NFB + 1];
  __shared__ int baseL[NFB];
  __shared__ int place[NFB];
  __shared__ unsigned stag[2048];
  __shared__ unsigned char cellb[2048];
  int cellc = blockIdx.x / BPC;
  int slice = blockIdx.x % BPC;
  int t = threadIdx.x;
  int cnt = min(curA[cellc], CAPA);
  const unsigned* in = bufA + (size_t)cellc * CAPA;
  for (int start = slice * 2048; start < cnt; start += BPC * 2048) {
    int n = min(2048, cnt - start);
    for (int i = t; i < NFB; i += 256) hist[i] = 0;
    __syncthreads();
    unsigned pv[8]; int pb[8];
#pragma unroll
    for (int i = 0; i < 8; ++i) {
      int idx = t + i * 256;
      if (idx < n) {
        unsigned w = in[start + idx];
        int dlow = (int)(w >> 17);
        int fb = dlow >> 5;
        pb[i] = fb;
        pv[i] = (w & 0x1FFFFu) | ((unsigned)(dlow & 31) << 17);
        atomicAdd(&hist[fb], 1);
      } else pb[i] = -1;
    }
    __syncthreads();
    if (t < 64) {
      int lane = t;
      int v = hist[lane];
      int x = v;
#pragma unroll
      for (int o = 1; o < 64; o <<= 1) {
        int y = __shfl_up(x, o, 64);
        if (lane >= o) x += y;
      }
      offsL[lane] = x - v;
      place[lane] = 0;
      if (v > 0) baseL[lane] = atomicAdd(&cur[cellc * NFB + lane], v);
      if (lane == 63) offsL[NFB] = x;
    }
    __syncthreads();
#pragma unroll
    for (int i = 0; i < 8; ++i) {
      if (pb[i] >= 0) {
        int p = atomicAdd(&place[pb[i]], 1);
        int sl = offsL[pb[i]] + p;
        stag[sl] = pv[i];
        cellb[sl] = (unsigned char)pb[i];
      }
    }
    __syncthreads();
    for (int s2 = t; s2 < n; s2 += 256) {
      int fb = cellb[s2];
      int pos = baseL[fb] + (s2 - offsL[fb]);
      if (pos < CAP) buf[(size_t)(cellc * NFB + fb) * CAP + pos] = stag[s2];
    }
    __syncthreads();
  }
}

// --------- single-block exclusive scan of bucket totals -> bbase ----------
__global__ __launch_bounds__(1024) void k_bscan(
    const int* __restrict__ cur, int* __restrict__ bbase) {
  __shared__ int warp_sums[16];
  __shared__ int s_running;
  int t = threadIdx.x;
  int lane = t & 63, w = t >> 6;
  if (t == 0) s_running = 0;
  __syncthreads();
  for (int base = 0; base < NB; base += 1024) {
    int i = base + t;
    int v = (i < NB) ? min(cur[i], CAP) : 0;
    int x = v;
#pragma unroll
    for (int o = 1; o < 64; o <<= 1) {
      int y = __shfl_up(x, o, 64);
      if (lane >= o) x += y;
    }
    if (lane == 63) warp_sums[w] = x;
    __syncthreads();
    if (w == 0) {
      int ws = (lane < 16) ? warp_sums[lane] : 0;
#pragma unroll
      for (int o = 1; o < 16; o <<= 1) {
        int y = __shfl_up(ws, o, 64);
        if (lane >= o) ws += y;
      }
      if (lane < 16) warp_sums[lane] = ws;
    }
    __syncthreads();
    int incl = x + (w > 0 ? warp_sums[w - 1] : 0);
    int excl = s_running + incl - v;
    if (i < NB) bbase[i] = excl;
    __syncthreads();
    if (t == 1023) s_running += incl;
    __syncthreads();
  }
}

// ------ block per bucket: LDS-staged count + prefix, dense CSR fill -------
__global__ __launch_bounds__(256) void k_bfill(
    const unsigned* __restrict__ buf, const int* __restrict__ cur,
    const int* __restrict__ bbase, int* __restrict__ deg,
    int* __restrict__ offs, int* __restrict__ eidx) {
  __shared__ int ncnt[NPB];
  __shared__ int ncur[NPB];
  __shared__ unsigned sbuf[CAP];
  int b = blockIdx.x, t = threadIdx.x;
  if (t < NPB) ncnt[t] = 0;
  __syncthreads();
  int nb = min(cur[b], CAP);
  const unsigned* bb = buf + (size_t)b * CAP;
  for (int slot = t; slot < nb; slot += 256) {
    unsigned w = bb[slot];
    sbuf[slot] = w;
    atomicAdd(&ncnt[w >> 17], 1);
  }
  __syncthreads();
  if (t < 64) {
    int lane = t;
    int c = (lane < NPB) ? ncnt[lane] : 0;
    int x = c;
#pragma unroll
    for (int o = 1; o < 32; o <<= 1) {
      int y = __shfl_up(x, o, 64);
      if (lane >= o) x += y;
    }
    if (lane < NPB) {
      int excl = x - c;
      ncur[lane] = excl;
      int gn = b * NPB + lane;
      deg[gn] = c;
      offs[gn] = bbase[b] + excl;
    }
  }
  __syncthreads();
  int base = bbase[b];
  for (int slot = t; slot < nb; slot += 256) {
    unsigned w = sbuf[slot];
    int p = atomicAdd(&ncur[w >> 17], 1);
    eidx[base + p] = (int)(w & 0x1FFFF);
  }
}

// ---- Gather layer 1, half-column pass: 4 nodes/wave, 16 lanes/node ------
// Half-tables (3.2 MB < 4 MB/XCD L2) keep gather rows L2-resident.
__global__ __launch_bounds__(256) void k_gather1(
    const unsigned short* __restrict__ xlbh, const float* __restrict__ xr,
    const int* __restrict__ offs, const int* __restrict__ deg,
    const int* __restrict__ eidx, const float* __restrict__ b1,
    const unsigned long long* __restrict__ msk1,
    unsigned short* __restrict__ hpbh) {
  int bb = blockIdx.x;
  int G = 0, nb = bb;
  if (nb >= GHB) { G = 1; nb -= GHB; }
  int tid = threadIdx.x;
  int lane = tid & 63;
  int node = nb * 16 + (tid >> 4);     // 16 nodes per block (6250*16 = 100000)
  int g = (tid >> 2) & 3;              // edge group within quarter
  int ch = tid & 3;                    // uint2 chunk of half-row
  int c = tid & 15;                    // column within half
  int col = G * 16 + c;
  int off = offs[node];
  int dg = deg[node];
  float xr_v = xr[node * 32 + col];    // hoisted, in flight during gather
  float b1_v = b1[col];
  unsigned jj = (unsigned)(node * 32 + col);
  unsigned long long mw = msk1[jj >> 6];   // hoisted mask word (L2 hit)
  const uint2* H = (const uint2*)(xlbh + (size_t)G * N16);
  v2f acc01 = {0.f, 0.f}, acc23 = {0.f, 0.f};
  int k = 0;
  for (; k + 8 <= dg; k += 8) {        // 8 edges/node/iter
    int s0 = eidx[off + k + g];
    int s1 = eidx[off + k + 4 + g];
    uint2 r0 = H[s0 * 4 + ch];
    uint2 r1 = H[s1 * 4 + ch];
    acc01 += up2(r0.x); acc23 += up2(r0.y);
    acc01 += up2(r1.x); acc23 += up2(r1.y);
  }
  for (; k < dg; k += 4) {
    if (k + g < dg) {
      int s = eidx[off + k + g];
      uint2 r = H[s * 4 + ch];
      acc01 += up2(r.x); acc23 += up2(r.y);
    }
  }
  float a0 = acc01.x, a1 = acc01.y, a2 = acc23.x, a3 = acc23.y;
  // reduce across the 4 groups (lane bits 2,3) — intra-quarter
  a0 += __shfl_xor(a0, 4, 64); a0 += __shfl_xor(a0, 8, 64);
  a1 += __shfl_xor(a1, 4, 64); a1 += __shfl_xor(a1, 8, 64);
  a2 += __shfl_xor(a2, 4, 64); a2 += __shfl_xor(a2, 8, 64);
  a3 += __shfl_xor(a3, 4, 64); a3 += __shfl_xor(a3, 8, 64);
  // redistribute: lane wants col c; source lane = quarter_base + (c>>2)
  int srcl = (lane & 48) + (c >> 2);
  float t0 = __shfl(a0, srcl, 64);
  float t1 = __shfl(a1, srcl, 64);
  float t2 = __shfl(a2, srcl, 64);
  float t3 = __shfl(a3, srcl, 64);
  int sub = lane & 3;
  float val = (sub == 0) ? t0 : (sub == 1) ? t1 : (sub == 2) ? t2 : t3;
  float inv = 1.0f / fmaxf((float)dg, 1.0f);
  float v = val * inv + b1_v + xr_v;
  v = (v > 0.f) ? v : 0.01f * v;
  float h = ((mw >> (jj & 63)) & 1ull) ? 2.0f * v : 0.0f;
  hpbh[(size_t)G * N16 + node * 16 + c] = f2bf(h);   // contiguous 128B/wave
}

// ---- Gather layer 2, half-column pass: mean-agg of hpb half-rows --------
__global__ __launch_bounds__(256) void k_gather2(
    const unsigned short* __restrict__ hpbh, const int* __restrict__ offs,
    const int* __restrict__ deg, const int* __restrict__ eidx,
    float* __restrict__ aggh) {
  int bb = blockIdx.x;
  int G = 0, nb = bb;
  if (nb >= GHB) { G = 1; nb -= GHB; }
  int tid = threadIdx.x;
  int lane = tid & 63;
  int node = nb * 16 + (tid >> 4);
  int g = (tid >> 2) & 3;
  int ch = tid & 3;
  int c = tid & 15;
  int off = offs[node];
  int dg = deg[node];
  const uint2* H = (const uint2*)(hpbh + (size_t)G * N16);
  v2f acc01 = {0.f, 0.f}, acc23 = {0.f, 0.f};
  int k = 0;
  for (; k + 8 <= dg; k += 8) {
    int s0 = eidx[off + k + g];
    int s1 = eidx[off + k + 4 + g];
    uint2 r0 = H[s0 * 4 + ch];
    uint2 r1 = H[s1 * 4 + ch];
    acc01 += up2(r0.x); acc23 += up2(r0.y);
    acc01 += up2(r1.x); acc23 += up2(r1.y);
  }
  for (; k < dg; k += 4) {
    if (k + g < dg) {
      int s = eidx[off + k + g];
      uint2 r = H[s * 4 + ch];
      acc01 += up2(r.x); acc23 += up2(r.y);
    }
  }
  float a0 = acc01.x, a1 = acc01.y, a2 = acc23.x, a3 = acc23.y;
  a0 += __shfl_xor(a0, 4, 64); a0 += __shfl_xor(a0, 8, 64);
  a1 += __shfl_xor(a1, 4, 64); a1 += __shfl_xor(a1, 8, 64);
  a2 += __shfl_xor(a2, 4, 64); a2 += __shfl_xor(a2, 8, 64);
  a3 += __shfl_xor(a3, 4, 64); a3 += __shfl_xor(a3, 8, 64);
  int srcl = (lane & 48) + (c >> 2);
  float t0 = __shfl(a0, srcl, 64);
  float t1 = __shfl(a1, srcl, 64);
  float t2 = __shfl(a2, srcl, 64);
  float t3 = __shfl(a3, srcl, 64);
  int sub = lane & 3;
  float val = (sub == 0) ? t0 : (sub == 1) ? t1 : (sub == 2) ? t2 : t3;
  float inv = 1.0f / fmaxf((float)dg, 1.0f);
  aggh[(size_t)G * N16 + node * 16 + c] = val * inv;  // contiguous 256B/wave
}

// ---- Final: one THREAD per node, spill-free two-pass --------------------
// Pass 1 computes ss only (dd recomputed in pass 2 with the identical FP
// sequence) — removes the d[64] register array that spilled in round 5.
// Rows ag/hf (64 regs) are the only live arrays. Weights via uniform
// s_load from transposed tables. No LDS, no shuffles, no broadcast reads.
__global__ __launch_bounds__(256, 3) void k_out2(
    const unsigned short* __restrict__ hpbh, const float* __restrict__ aggh,
    const float* __restrict__ W2lT, const float* __restrict__ b2,
    const float* __restrict__ W2rT, const unsigned long long* __restrict__ msk2,
    float* __restrict__ out) {
  int node = blockIdx.x * 256 + threadIdx.x;
  if (node >= N_NODES) return;
  float ag[32];
  const float4* a0p = (const float4*)(aggh + (size_t)node * 16);
  const float4* a1p = (const float4*)(aggh + (size_t)N16 + (size_t)node * 16);
#pragma unroll
  for (int i = 0; i < 4; ++i) ((float4*)ag)[i] = a0p[i];
#pragma unroll
  for (int i = 0; i < 4; ++i) ((float4*)(ag + 16))[i] = a1p[i];
  float hf[32];
  {
    const uint4* h0 = (const uint4*)(hpbh + (size_t)node * 16);
    const uint4* h1 = (const uint4*)(hpbh + (size_t)N16 + (size_t)node * 16);
    uint4 ua = h0[0], ub = h0[1], uc = h1[0], ud = h1[1];
    v2f t;
    t = up2(ua.x); hf[0] = t.x;  hf[1] = t.y;
    t = up2(ua.y); hf[2] = t.x;  hf[3] = t.y;
    t = up2(ua.z); hf[4] = t.x;  hf[5] = t.y;
    t = up2(ua.w); hf[6] = t.x;  hf[7] = t.y;
    t = up2(ub.x); hf[8] = t.x;  hf[9] = t.y;
    t = up2(ub.y); hf[10] = t.x; hf[11] = t.y;
    t = up2(ub.z); hf[12] = t.x; hf[13] = t.y;
    t = up2(ub.w); hf[14] = t.x; hf[15] = t.y;
    t = up2(uc.x); hf[16] = t.x; hf[17] = t.y;
    t = up2(uc.y); hf[18] = t.x; hf[19] = t.y;
    t = up2(uc.z); hf[20] = t.x; hf[21] = t.y;
    t = up2(uc.w); hf[22] = t.x; hf[23] = t.y;
    t = up2(ud.x); hf[24] = t.x; hf[25] = t.y;
    t = up2(ud.y); hf[26] = t.x; hf[27] = t.y;
    t = up2(ud.z); hf[28] = t.x; hf[29] = t.y;
    t = up2(ud.w); hf[30] = t.x; hf[31] = t.y;
  }
  unsigned long long mw = msk2[node];
  // pass 1: sum of squares only
  float ss = 0.f;
#pragma unroll 8
  for (int c = 0; c < 64; ++c) {
    const float* wl = W2lT + c * 32;
    const float* wr = W2rT + c * 32;
    float s0 = 0.f, s1 = 0.f;
#pragma unroll
    for (int k = 0; k < 32; ++k) { s0 += ag[k] * wl[k]; s1 += hf[k] * wr[k]; }
    float v = s0 + s1 + b2[c];
    float dd = ((mw >> c) & 1ull) ? 2.0f * v : 0.0f;
    ss += dd * dd;
  }
  float scale = 1.0f / fmaxf(sqrtf(ss), 1e-12f);
  // pass 2: recompute (identical sequence) and store scaled, float4-packed
  float4* op = (float4*)(out + (size_t)node * 64);
#pragma unroll 4
  for (int i = 0; i < 16; ++i) {
    float r[4];
#pragma unroll
    for (int j = 0; j < 4; ++j) {
      int c = i * 4 + j;
      const float* wl = W2lT + c * 32;
      const float* wr = W2rT + c * 32;
      float s0 = 0.f, s1 = 0.f;
#pragma unroll
      for (int k = 0; k < 32; ++k) { s0 += ag[k] * wl[k]; s1 += hf[k] * wr[k]; }
      float v = s0 + s1 + b2[c];
      float dd = ((mw >> c) & 1ull) ? 2.0f * v : 0.0f;
      r[j] = dd * scale;
    }
    op[i] = make_float4(r[0], r[1], r[2], r[3]);
  }
}

// --------------------------------------------------------------------------
extern "C" void kernel_launch(void* const* d_in, const int* in_sizes, int n_in,
                              void* d_out, int out_size, void* d_ws, size_t ws_size,
                              hipStream_t stream) {
  const float* x   = (const float*)d_in[0];
  const int*   ei  = (const int*)d_in[1];
  const float* W1l = (const float*)d_in[2];
  const float* b1  = (const float*)d_in[3];
  const float* W1r = (const float*)d_in[4];
  const float* W2l = (const float*)d_in[5];
  const float* b2  = (const float*)d_in[6];
  const float* W2r = (const float*)d_in[7];
  float* out = (float*)d_out;

  const int* src = ei;            // edge_index[0]
  const int* dst = ei + N_EDGES;  // edge_index[1]

  const size_t F32 = (size_t)N_NODES * 32;
  char* w = (char*)d_ws;
  // region 1 (12.8 MB): bufA (binning) -> xr (transform/gather1) -> aggh (gather2/out2)
  unsigned* bufA = (unsigned*)w;                 // 49*34816*4 = 6.8 MB
  float* xr      = (float*)w;                    // 12.8 MB (bufA dead by then)
  float* aggh    = (float*)w;                    // 12.8 MB (xr dead after gather1)
  w += F32 * sizeof(float);
  // region 2 (12.8 MB): buf (binning) -> xlbh[2] + hpbh[2] half-tables
  unsigned* buf  = (unsigned*)w;                 // 3125*704*4 = 8.8 MB
  unsigned short* xlbh = (unsigned short*)w;     // 2 x 3.2 MB
  unsigned short* hpbh = xlbh + 2 * (size_t)N16; // 2 x 3.2 MB (buf dead by then)
  w += F32 * 2 * sizeof(unsigned short);
  int* curA  = (int*)w; w += NCC * sizeof(int);
  int* cur   = (int*)w; w += NB * sizeof(int);
  int* bbase = (int*)w; w += NB * sizeof(int);
  int* deg   = (int*)w; w += N_NODES * sizeof(int);
  int* offs  = (int*)w; w += N_NODES * sizeof(int);
  int* eidx  = (int*)w; w += (size_t)N_EDGES * sizeof(int);   // 6.4 MB (dense)
  unsigned long long* msk = (unsigned long long*)w;           // 1.2 MB masks
  w += (size_t)(M1W + M2W) * sizeof(unsigned long long);
  float* wt = (float*)w;                                      // 32 KB transposed W
  float* W1lT = wt;
  float* W1rT = wt + 2048;
  float* W2lT = wt + 4096;
  float* W2rT = wt + 6144;

  hipMemsetAsync(curA, 0, (size_t)(NCC + NB) * sizeof(int), stream);

  k_mask<<<2048, 256, 0, stream>>>(msk, W1l, W1r, W2l, W2r, wt);
  k_binA<<<(N_EDGES + 2047) / 2048, 256, 0, stream>>>(src, dst, curA, bufA);
  k_binB<<<NCC * BPC, 256, 0, stream>>>(bufA, curA, cur, buf);
  k_bscan<<<1, 1024, 0, stream>>>(cur, bbase);
  k_bfill<<<NB, 256, 0, stream>>>(buf, cur, bbase, deg, offs, eidx);

  k_transform1<<<(N_NODES + 255) / 256, 256, 0, stream>>>(x, W1lT, W1rT, xlbh, xr);
  k_gather1<<<2 * GHB, 256, 0, stream>>>(xlbh, xr, offs, deg, eidx, b1, msk, hpbh);
  k_gather2<<<2 * GHB, 256, 0, stream>>>(hpbh, offs, deg, eidx, aggh);
  k_out2<<<(N_NODES + 255) / 256, 256, 0, stream>>>(hpbh, aggh, W2lT, b2, W2rT, msk + M1W, out);
}

// Round 8
// 285.932 us; speedup vs baseline: 1.2085x; 1.2085x over previous
//
#include <hip/hip_runtime.h>

#define N_NODES 100000
#define N_EDGES 1600000
#define NPB 32                       // nodes per bucket (dst >> 5)
#define NB (N_NODES / NPB)           // 3125 buckets
#define CAP 704                      // slots per bucket (mean 512 + 8.5 sigma)
#define NCC 49                       // coarse cells (dst >> 11)
#define CAPA 34816                   // slots per coarse cell (mean 32768 + 11 sigma)
#define NFB 64                       // fine buckets per coarse cell
#define BPC 16                       // blocks per cell in pass B
#define N16 (N_NODES * 16)           // elements per half-table (16 cols/node)
#define GHB 6250                     // node-blocks per half-pass (6250*16 = 100000)
#define M1W 50000                    // mask1 u64 words (N*32/64)
#define M2W 100000                   // mask2 u64 words (N*64/64)

typedef float v2f __attribute__((ext_vector_type(2)));

// Opaque register pin: after this, the compiler cannot rematerialize the
// value from memory (asm may have changed it) — it MUST live in VGPRs.
// Rounds 1/4 proved hipcc sinks loop-invariant weight loads (VGPR 52/56);
// rounds 5/6 proved per-thread arrays spill (WRITE_SIZE 97 MB). This is the
// only source-level mechanism left that forces register residency.
#define PIN4(v) asm volatile("" : "+v"(v.x), "+v"(v.y), "+v"(v.z), "+v"(v.w))

// ---------------- JAX threefry2x32 (partitionable scheme) ----------------
struct U2 { unsigned a, b; };

__host__ __device__ constexpr U2 tf2x32(unsigned k0, unsigned k1, unsigned c0, unsigned c1) {
  unsigned ks2 = k0 ^ k1 ^ 0x1BD11BDAu;
  unsigned x0 = c0 + k0, x1 = c1 + k1;
#define TFR(r) { x0 += x1; x1 = (x1 << (r)) | (x1 >> (32 - (r))); x1 ^= x0; }
  TFR(13) TFR(15) TFR(26) TFR(6)
  x0 += k1;  x1 += ks2 + 1u;
  TFR(17) TFR(29) TFR(16) TFR(24)
  x0 += ks2; x1 += k0 + 2u;
  TFR(13) TFR(15) TFR(26) TFR(6)
  x0 += k0;  x1 += k1 + 3u;
  TFR(17) TFR(29) TFR(16) TFR(24)
  x0 += k1;  x1 += ks2 + 4u;
  TFR(13) TFR(15) TFR(26) TFR(6)
  x0 += ks2; x1 += k0 + 5u;
#undef TFR
  return U2{x0, x1};
}

constexpr U2 DK0 = tf2x32(0u, 42u, 0u, 0u);
constexpr U2 DK1 = tf2x32(0u, 42u, 0u, 1u);

__device__ __forceinline__ bool keep_bit(unsigned k0, unsigned k1, unsigned j) {
  U2 w = tf2x32(k0, k1, 0u, j);
  return ((w.a ^ w.b) >> 31) == 0u;
}

// bf16 storage helpers (RNE pack, shift unpack)
__device__ __forceinline__ unsigned short f2bf(float f) {
  unsigned u = __float_as_uint(f);
  u += 0x7FFFu + ((u >> 16) & 1u);
  return (unsigned short)(u >> 16);
}
// unpack uint32 (2 bf16) -> v2f
__device__ __forceinline__ v2f up2(unsigned r) {
  v2f v;
  v.x = __uint_as_float(r << 16);
  v.y = __uint_as_float(r & 0xFFFF0000u);
  return v;
}

// weight column quad: W[(4i..4i+3)][lane] with leading dim ld (i literal)
__device__ __forceinline__ float4 ldcol(const float* __restrict__ W, int i,
                                        int lane, int ld) {
  float4 v;
  v.x = W[(i * 4 + 0) * ld + lane];
  v.y = W[(i * 4 + 1) * ld + lane];
  v.z = W[(i * 4 + 2) * ld + lane];
  v.w = W[(i * 4 + 3) * ld + lane];
  return v;
}

// ------ Mask precompute: both dropout masks, 1 bit/element ---------------
__global__ __launch_bounds__(256) void k_mask(unsigned long long* __restrict__ msk) {
  int w = (int)((blockIdx.x * blockDim.x + threadIdx.x) >> 6);
  int lane = threadIdx.x & 63;
  int nw = (int)((gridDim.x * blockDim.x) >> 6);
  for (; w < M1W + M2W; w += nw) {
    unsigned k0, k1, j;
    if (w < M1W) { k0 = DK0.a; k1 = DK0.b; j = (unsigned)w * 64u + (unsigned)lane; }
    else { k0 = DK1.a; k1 = DK1.b; j = (unsigned)(w - M1W) * 64u + (unsigned)lane; }
    unsigned long long bits = __ballot(keep_bit(k0, k1, j));
    if (lane == 0) msk[w] = bits;
  }
}

// ------ Kernel A: xl = bf16(x@W1_l) into 2 half-tables, xr = x@W1_r ------
// Wave-per-node persistent; weight column (64 f32/lane) PINNED in VGPRs via
// opaque asm. Double-buffered LDS row staging with next-node prefetch.
__global__ __launch_bounds__(256, 4) void k_transform1(
    const float* __restrict__ x, const float* __restrict__ Wl,
    const float* __restrict__ Wr, unsigned short* __restrict__ xlbh,
    float* __restrict__ xr) {
  __shared__ __align__(16) float rv[2][4][64];
  int lane = threadIdx.x & 63;
  int wv = (threadIdx.x >> 6) & 3;
  const float* W = (lane < 32) ? Wl : Wr;
  int c = lane & 31;
  float4 V0 = ldcol(W, 0, c, 32);   PIN4(V0);
  float4 V1 = ldcol(W, 1, c, 32);   PIN4(V1);
  float4 V2 = ldcol(W, 2, c, 32);   PIN4(V2);
  float4 V3 = ldcol(W, 3, c, 32);   PIN4(V3);
  float4 V4 = ldcol(W, 4, c, 32);   PIN4(V4);
  float4 V5 = ldcol(W, 5, c, 32);   PIN4(V5);
  float4 V6 = ldcol(W, 6, c, 32);   PIN4(V6);
  float4 V7 = ldcol(W, 7, c, 32);   PIN4(V7);
  float4 V8 = ldcol(W, 8, c, 32);   PIN4(V8);
  float4 V9 = ldcol(W, 9, c, 32);   PIN4(V9);
  float4 V10 = ldcol(W, 10, c, 32); PIN4(V10);
  float4 V11 = ldcol(W, 11, c, 32); PIN4(V11);
  float4 V12 = ldcol(W, 12, c, 32); PIN4(V12);
  float4 V13 = ldcol(W, 13, c, 32); PIN4(V13);
  float4 V14 = ldcol(W, 14, c, 32); PIN4(V14);
  float4 V15 = ldcol(W, 15, c, 32); PIN4(V15);
  int wid0 = (int)((blockIdx.x * blockDim.x + threadIdx.x) >> 6);
  int wstride = (int)((gridDim.x * blockDim.x) >> 6);
  float xv = x[wid0 * 64 + lane];      // prologue prefetch
  int b = 0;
  for (int wid = wid0; wid < N_NODES; wid += wstride) {
    rv[b][wv][lane] = xv;              // staged row
    int nxt = wid + wstride;
    if (nxt < N_NODES) xv = x[nxt * 64 + lane];   // prefetch under GEMM
    asm volatile("s_waitcnt lgkmcnt(0)" ::: "memory");   // same-wave LDS drain
    const float* rb = &rv[b][wv][0];
    v2f s0 = {0.f, 0.f}, s1 = {0.f, 0.f};
#define TST(Vi, i) { \
    float4 r = *(const float4*)(rb + (i) * 4); \
    v2f w0; w0.x = Vi.x; w0.y = Vi.y; \
    v2f w1; w1.x = Vi.z; w1.y = Vi.w; \
    v2f p0; p0.x = r.x; p0.y = r.y; \
    v2f p1; p1.x = r.z; p1.y = r.w; \
    s0 += p0 * w0; s1 += p1 * w1; }
    TST(V0, 0)  TST(V1, 1)  TST(V2, 2)  TST(V3, 3)
    TST(V4, 4)  TST(V5, 5)  TST(V6, 6)  TST(V7, 7)
    TST(V8, 8)  TST(V9, 9)  TST(V10, 10) TST(V11, 11)
    TST(V12, 12) TST(V13, 13) TST(V14, 14) TST(V15, 15)
#undef TST
    float s = (s0.x + s0.y) + (s1.x + s1.y);
    if (lane < 32) xlbh[(size_t)(c >> 4) * N16 + wid * 16 + (c & 15)] = f2bf(s);
    else           xr[wid * 32 + c] = s;
    b ^= 1;
  }
}

// ------ Pass A: LDS-staged partition by coarse cell (dst>>11), 49 cells ---
__global__ __launch_bounds__(256) void k_binA(
    const int* __restrict__ src, const int* __restrict__ dst,
    int* __restrict__ curA, unsigned* __restrict__ bufA) {
  __shared__ int hist[NCC];
  __shared__ int offsL[NCC + 1];
  __shared__ int baseL[NCC];
  __shared__ int place[NCC];
  __shared__ unsigned stag[2048];
  __shared__ unsigned char cellb[2048];
  int t = threadIdx.x;
  for (long long start = (long long)blockIdx.x * 2048; start < N_EDGES;
       start += (long long)gridDim.x * 2048) {
    int n = (int)min((long long)2048, (long long)N_EDGES - start);
    for (int i = t; i < NCC; i += 256) hist[i] = 0;
    __syncthreads();
    unsigned pv[8]; int pc[8];
#pragma unroll
    for (int i = 0; i < 8; ++i) {
      int idx = t + i * 256;
      if (idx < n) {
        int d = dst[start + idx];
        int s = src[start + idx];
        int cc = d >> 11;
        pc[i] = cc;
        pv[i] = (unsigned)s | ((unsigned)(d & 2047) << 17);
        atomicAdd(&hist[cc], 1);
      } else pc[i] = -1;
    }
    __syncthreads();
    if (t < 64) {
      int lane = t;
      int v = (lane < NCC) ? hist[lane] : 0;
      int x = v;
#pragma unroll
      for (int o = 1; o < 64; o <<= 1) {
        int y = __shfl_up(x, o, 64);
        if (lane >= o) x += y;
      }
      if (lane < NCC) {
        offsL[lane] = x - v;
        place[lane] = 0;
        if (v > 0) baseL[lane] = atomicAdd(&curA[lane], v);
      }
      if (lane == NCC - 1) offsL[NCC] = x;
    }
    __syncthreads();
#pragma unroll
    for (int i = 0; i < 8; ++i) {
      if (pc[i] >= 0) {
        int p = atomicAdd(&place[pc[i]], 1);
        int sl = offsL[pc[i]] + p;
        stag[sl] = pv[i];
        cellb[sl] = (unsigned char)pc[i];
      }
    }
    __syncthreads();
    for (int s2 = t; s2 < n; s2 += 256) {     // coalesced copy-out, no search
      int cell = cellb[s2];
      int pos = baseL[cell] + (s2 - offsL[cell]);
      if (pos < CAPA) bufA[(size_t)cell * CAPA + pos] = stag[s2];
    }
    __syncthreads();
  }
}

// ------ Pass B: refine each coarse cell into 64 fine buckets -------------
__global__ __launch_bounds__(256) void k_binB(
    const unsigned* __restrict__ bufA, const int* __restrict__ curA,
    int* __restrict__ cur, unsigned* __restrict__ buf) {
  __shared__ int hist[NFB];
  __shared__ int offsL[NFB + 1];
  __shared__ int baseL[NFB];
  __shared__ int place[NFB];
  __shared__ unsigned stag[2048];
  __shared__ unsigned char cellb[2048];
  int cellc = blockIdx.x / BPC;
  int slice = blockIdx.x % BPC;
  int t = threadIdx.x;
  int cnt = min(curA[cellc], CAPA);
  const unsigned* in = bufA + (size_t)cellc * CAPA;
  for (int start = slice * 2048; start < cnt; start += BPC * 2048) {
    int n = min(2048, cnt - start);
    for (int i = t; i < NFB; i += 256) hist[i] = 0;
    __syncthreads();
    unsigned pv[8]; int pb[8];
#pragma unroll
    for (int i = 0; i < 8; ++i) {
      int idx = t + i * 256;
      if (idx < n) {
        unsigned w = in[start + idx];
        int dlow = (int)(w >> 17);
        int fb = dlow >> 5;
        pb[i] = fb;
        pv[i] = (w & 0x1FFFFu) | ((unsigned)(dlow & 31) << 17);
        atomicAdd(&hist[fb], 1);
      } else pb[i] = -1;
    }
    __syncthreads();
    if (t < 64) {
      int lane = t;
      int v = hist[lane];
      int x = v;
#pragma unroll
      for (int o = 1; o < 64; o <<= 1) {
        int y = __shfl_up(x, o, 64);
        if (lane >= o) x += y;
      }
      offsL[lane] = x - v;
      place[lane] = 0;
      if (v > 0) baseL[lane] = atomicAdd(&cur[cellc * NFB + lane], v);
      if (lane == 63) offsL[NFB] = x;
    }
    __syncthreads();
#pragma unroll
    for (int i = 0; i < 8; ++i) {
      if (pb[i] >= 0) {
        int p = atomicAdd(&place[pb[i]], 1);
        int sl = offsL[pb[i]] + p;
        stag[sl] = pv[i];
        cellb[sl] = (unsigned char)pb[i];
      }
    }
    __syncthreads();
    for (int s2 = t; s2 < n; s2 += 256) {
      int fb = cellb[s2];
      int pos = baseL[fb] + (s2 - offsL[fb]);
      if (pos < CAP) buf[(size_t)(cellc * NFB + fb) * CAP + pos] = stag[s2];
    }
    __syncthreads();
  }
}

// --------- single-block exclusive scan of bucket totals -> bbase ----------
__global__ __launch_bounds__(1024) void k_bscan(
    const int* __restrict__ cur, int* __restrict__ bbase) {
  __shared__ int warp_sums[16];
  __shared__ int s_running;
  int t = threadIdx.x;
  int lane = t & 63, w = t >> 6;
  if (t == 0) s_running = 0;
  __syncthreads();
  for (int base = 0; base < NB; base += 1024) {
    int i = base + t;
    int v = (i < NB) ? min(cur[i], CAP) : 0;
    int x = v;
#pragma unroll
    for (int o = 1; o < 64; o <<= 1) {
      int y = __shfl_up(x, o, 64);
      if (lane >= o) x += y;
    }
    if (lane == 63) warp_sums[w] = x;
    __syncthreads();
    if (w == 0) {
      int ws = (lane < 16) ? warp_sums[lane] : 0;
#pragma unroll
      for (int o = 1; o < 16; o <<= 1) {
        int y = __shfl_up(ws, o, 64);
        if (lane >= o) ws += y;
      }
      if (lane < 16) warp_sums[lane] = ws;
    }
    __syncthreads();
    int incl = x + (w > 0 ? warp_sums[w - 1] : 0);
    int excl = s_running + incl - v;
    if (i < NB) bbase[i] = excl;
    __syncthreads();
    if (t == 1023) s_running += incl;
    __syncthreads();
  }
}

// ------ block per bucket: LDS-staged count + prefix, dense CSR fill -------
__global__ __launch_bounds__(256) void k_bfill(
    const unsigned* __restrict__ buf, const int* __restrict__ cur,
    const int* __restrict__ bbase, int* __restrict__ deg,
    int* __restrict__ offs, int* __restrict__ eidx) {
  __shared__ int ncnt[NPB];
  __shared__ int ncur[NPB];
  __shared__ unsigned sbuf[CAP];
  int b = blockIdx.x, t = threadIdx.x;
  if (t < NPB) ncnt[t] = 0;
  __syncthreads();
  int nb = min(cur[b], CAP);
  const unsigned* bb = buf + (size_t)b * CAP;
  for (int slot = t; slot < nb; slot += 256) {
    unsigned w = bb[slot];
    sbuf[slot] = w;
    atomicAdd(&ncnt[w >> 17], 1);
  }
  __syncthreads();
  if (t < 64) {
    int lane = t;
    int c = (lane < NPB) ? ncnt[lane] : 0;
    int x = c;
#pragma unroll
    for (int o = 1; o < 32; o <<= 1) {
      int y = __shfl_up(x, o, 64);
      if (lane >= o) x += y;
    }
    if (lane < NPB) {
      int excl = x - c;
      ncur[lane] = excl;
      int gn = b * NPB + lane;
      deg[gn] = c;
      offs[gn] = bbase[b] + excl;
    }
  }
  __syncthreads();
  int base = bbase[b];
  for (int slot = t; slot < nb; slot += 256) {
    unsigned w = sbuf[slot];
    int p = atomicAdd(&ncur[w >> 17], 1);
    eidx[base + p] = (int)(w & 0x1FFFF);
  }
}

// ---- Gather layer 1, half-column pass: 4 nodes/wave, 16 lanes/node ------
// Half-tables (3.2 MB < 4 MB/XCD L2) keep gather rows L2-resident.
// Dropout bit from the precomputed mask word.
__global__ __launch_bounds__(256) void k_gather1(
    const unsigned short* __restrict__ xlbh, const float* __restrict__ xr,
    const int* __restrict__ offs, const int* __restrict__ deg,
    const int* __restrict__ eidx, const float* __restrict__ b1,
    const unsigned long long* __restrict__ msk1,
    unsigned short* __restrict__ hpbh) {
  int bb = blockIdx.x;
  int G = 0, nb = bb;
  if (nb >= GHB) { G = 1; nb -= GHB; }
  int tid = threadIdx.x;
  int lane = tid & 63;
  int node = nb * 16 + (tid >> 4);     // 16 nodes per block (6250*16 = 100000)
  int g = (tid >> 2) & 3;              // edge group within quarter
  int ch = tid & 3;                    // uint2 chunk of half-row
  int c = tid & 15;                    // column within half
  int col = G * 16 + c;
  int off = offs[node];
  int dg = deg[node];
  float xr_v = xr[node * 32 + col];    // hoisted, in flight during gather
  float b1_v = b1[col];
  unsigned jj = (unsigned)(node * 32 + col);
  unsigned long long mw = msk1[jj >> 6];   // hoisted mask word (L2 hit)
  const uint2* H = (const uint2*)(xlbh + (size_t)G * N16);
  v2f acc01 = {0.f, 0.f}, acc23 = {0.f, 0.f};
  int k = 0;
  for (; k + 8 <= dg; k += 8) {        // 8 edges/node/iter
    int s0 = eidx[off + k + g];
    int s1 = eidx[off + k + 4 + g];
    uint2 r0 = H[s0 * 4 + ch];
    uint2 r1 = H[s1 * 4 + ch];
    acc01 += up2(r0.x); acc23 += up2(r0.y);
    acc01 += up2(r1.x); acc23 += up2(r1.y);
  }
  for (; k < dg; k += 4) {
    if (k + g < dg) {
      int s = eidx[off + k + g];
      uint2 r = H[s * 4 + ch];
      acc01 += up2(r.x); acc23 += up2(r.y);
    }
  }
  float a0 = acc01.x, a1 = acc01.y, a2 = acc23.x, a3 = acc23.y;
  // reduce across the 4 groups (lane bits 2,3) — intra-quarter
  a0 += __shfl_xor(a0, 4, 64); a0 += __shfl_xor(a0, 8, 64);
  a1 += __shfl_xor(a1, 4, 64); a1 += __shfl_xor(a1, 8, 64);
  a2 += __shfl_xor(a2, 4, 64); a2 += __shfl_xor(a2, 8, 64);
  a3 += __shfl_xor(a3, 4, 64); a3 += __shfl_xor(a3, 8, 64);
  // redistribute: lane wants col c; source lane = quarter_base + (c>>2)
  int srcl = (lane & 48) + (c >> 2);
  float t0 = __shfl(a0, srcl, 64);
  float t1 = __shfl(a1, srcl, 64);
  float t2 = __shfl(a2, srcl, 64);
  float t3 = __shfl(a3, srcl, 64);
  int sub = lane & 3;
  float val = (sub == 0) ? t0 : (sub == 1) ? t1 : (sub == 2) ? t2 : t3;
  float inv = 1.0f / fmaxf((float)dg, 1.0f);
  float v = val * inv + b1_v + xr_v;
  v = (v > 0.f) ? v : 0.01f * v;
  float h = ((mw >> (jj & 63)) & 1ull) ? 2.0f * v : 0.0f;
  hpbh[(size_t)G * N16 + node * 16 + c] = f2bf(h);   // contiguous 128B/wave
}

// ---- Gather layer 2, half-column pass: mean-agg of hpb half-rows --------
__global__ __launch_bounds__(256) void k_gather2(
    const unsigned short* __restrict__ hpbh, const int* __restrict__ offs,
    const int* __restrict__ deg, const int* __restrict__ eidx,
    float* __restrict__ aggh) {
  int bb = blockIdx.x;
  int G = 0, nb = bb;
  if (nb >= GHB) { G = 1; nb -= GHB; }
  int tid = threadIdx.x;
  int lane = tid & 63;
  int node = nb * 16 + (tid >> 4);
  int g = (tid >> 2) & 3;
  int ch = tid & 3;
  int c = tid & 15;
  int off = offs[node];
  int dg = deg[node];
  const uint2* H = (const uint2*)(hpbh + (size_t)G * N16);
  v2f acc01 = {0.f, 0.f}, acc23 = {0.f, 0.f};
  int k = 0;
  for (; k + 8 <= dg; k += 8) {
    int s0 = eidx[off + k + g];
    int s1 = eidx[off + k + 4 + g];
    uint2 r0 = H[s0 * 4 + ch];
    uint2 r1 = H[s1 * 4 + ch];
    acc01 += up2(r0.x); acc23 += up2(r0.y);
    acc01 += up2(r1.x); acc23 += up2(r1.y);
  }
  for (; k < dg; k += 4) {
    if (k + g < dg) {
      int s = eidx[off + k + g];
      uint2 r = H[s * 4 + ch];
      acc01 += up2(r.x); acc23 += up2(r.y);
    }
  }
  float a0 = acc01.x, a1 = acc01.y, a2 = acc23.x, a3 = acc23.y;
  a0 += __shfl_xor(a0, 4, 64); a0 += __shfl_xor(a0, 8, 64);
  a1 += __shfl_xor(a1, 4, 64); a1 += __shfl_xor(a1, 8, 64);
  a2 += __shfl_xor(a2, 4, 64); a2 += __shfl_xor(a2, 8, 64);
  a3 += __shfl_xor(a3, 4, 64); a3 += __shfl_xor(a3, 8, 64);
  int srcl = (lane & 48) + (c >> 2);
  float t0 = __shfl(a0, srcl, 64);
  float t1 = __shfl(a1, srcl, 64);
  float t2 = __shfl(a2, srcl, 64);
  float t3 = __shfl(a3, srcl, 64);
  int sub = lane & 3;
  float val = (sub == 0) ? t0 : (sub == 1) ? t1 : (sub == 2) ? t2 : t3;
  float inv = 1.0f / fmaxf((float)dg, 1.0f);
  aggh[(size_t)G * N16 + node * 16 + c] = val * inv;  // contiguous 256B/wave
}

// ---- Final: wave-per-node GEMM, weights PINNED in VGPRs (64/lane) -------
// Dbuf LDS row staging + next-node prefetch; precomputed dropout mask;
// L2 norm via 6-step shfl reduce. No in-loop weight traffic.
__global__ __launch_bounds__(256, 4) void k_out2(
    const unsigned short* __restrict__ hpbh, const float* __restrict__ aggh,
    const float* __restrict__ W2l, const float* __restrict__ b2,
    const float* __restrict__ W2r, const unsigned long long* __restrict__ msk2,
    float* __restrict__ out) {
  __shared__ __align__(16) float rv[2][4][64];
  int lane = threadIdx.x & 63;
  int wv = (threadIdx.x >> 6) & 3;
  float4 L0 = ldcol(W2l, 0, lane, 64); PIN4(L0);
  float4 L1 = ldcol(W2l, 1, lane, 64); PIN4(L1);
  float4 L2 = ldcol(W2l, 2, lane, 64); PIN4(L2);
  float4 L3 = ldcol(W2l, 3, lane, 64); PIN4(L3);
  float4 L4 = ldcol(W2l, 4, lane, 64); PIN4(L4);
  float4 L5 = ldcol(W2l, 5, lane, 64); PIN4(L5);
  float4 L6 = ldcol(W2l, 6, lane, 64); PIN4(L6);
  float4 L7 = ldcol(W2l, 7, lane, 64); PIN4(L7);
  float4 R0 = ldcol(W2r, 0, lane, 64); PIN4(R0);
  float4 R1 = ldcol(W2r, 1, lane, 64); PIN4(R1);
  float4 R2 = ldcol(W2r, 2, lane, 64); PIN4(R2);
  float4 R3 = ldcol(W2r, 3, lane, 64); PIN4(R3);
  float4 R4 = ldcol(W2r, 4, lane, 64); PIN4(R4);
  float4 R5 = ldcol(W2r, 5, lane, 64); PIN4(R5);
  float4 R6 = ldcol(W2r, 6, lane, 64); PIN4(R6);
  float4 R7 = ldcol(W2r, 7, lane, 64); PIN4(R7);
  float bias = b2[lane];
  int wid0 = (int)((blockIdx.x * blockDim.x + threadIdx.x) >> 6);
  int wstride = (int)((gridDim.x * blockDim.x) >> 6);
  float4 pa; uint2 ph;
#define PRELOAD(widx) { \
  if (lane < 8) { \
    const float* ap = aggh + ((lane < 4) ? 0 : (size_t)N16) + (size_t)(widx) * 16 + (lane & 3) * 4; \
    pa = *(const float4*)ap; \
  } else if (lane < 16) { \
    const uint2* Hp = (const uint2*)(hpbh + ((lane < 12) ? 0 : (size_t)N16)); \
    ph = Hp[(size_t)(widx) * 4 + (lane & 3)]; \
  } }
  PRELOAD(wid0);                       // prologue
  int b = 0;
  for (int wid = wid0; wid < N_NODES; wid += wstride) {
    if (lane < 8) {                    // agg row: cols lane*4..lane*4+3
      *(float4*)&rv[b][wv][lane * 4] = pa;
    } else if (lane < 16) {            // own hp row: cols (lane-8)*4..+3
      v2f lo = up2(ph.x), hi = up2(ph.y);
      float4 v; v.x = lo.x; v.y = lo.y; v.z = hi.x; v.w = hi.y;
      *(float4*)&rv[b][wv][32 + (lane - 8) * 4] = v;
    }
    int nxt = wid + wstride;
    if (nxt < N_NODES) PRELOAD(nxt);   // prefetch under GEMM
    unsigned long long mw = msk2[wid]; // wave-uniform mask word, in flight
    asm volatile("s_waitcnt lgkmcnt(0)" ::: "memory");   // same-wave LDS drain
    const float* rb = &rv[b][wv][0];
    v2f sa = {0.f, 0.f}, sb = {0.f, 0.f};
#define GST(Li, Ri, i) { \
    float4 r1 = *(const float4*)(rb + (i) * 4); \
    float4 r2 = *(const float4*)(rb + 32 + (i) * 4); \
    v2f w0; w0.x = Li.x; w0.y = Li.y; \
    v2f w1; w1.x = Li.z; w1.y = Li.w; \
    v2f u0; u0.x = Ri.x; u0.y = Ri.y; \
    v2f u1; u1.x = Ri.z; u1.y = Ri.w; \
    v2f p0; p0.x = r1.x; p0.y = r1.y; \
    v2f p1; p1.x = r1.z; p1.y = r1.w; \
    v2f q0; q0.x = r2.x; q0.y = r2.y; \
    v2f q1; q1.x = r2.z; q1.y = r2.w; \
    sa += p0 * w0; sa += p1 * w1; \
    sb += q0 * u0; sb += q1 * u1; }
    GST(L0, R0, 0) GST(L1, R1, 1) GST(L2, R2, 2) GST(L3, R3, 3)
    GST(L4, R4, 4) GST(L5, R5, 5) GST(L6, R6, 6) GST(L7, R7, 7)
#undef GST
    float v = (sa.x + sa.y) + (sb.x + sb.y) + bias;
    float d = ((mw >> lane) & 1ull) ? 2.0f * v : 0.0f;
    float ss = d * d;
#pragma unroll
    for (int o = 32; o > 0; o >>= 1) ss += __shfl_xor(ss, o, 64);
    float scale = 1.0f / fmaxf(sqrtf(ss), 1e-12f);
    out[(size_t)wid * 64 + lane] = d * scale;
    b ^= 1;
  }
#undef PRELOAD
}

// --------------------------------------------------------------------------
extern "C" void kernel_launch(void* const* d_in, const int* in_sizes, int n_in,
                              void* d_out, int out_size, void* d_ws, size_t ws_size,
                              hipStream_t stream) {
  const float* x   = (const float*)d_in[0];
  const int*   ei  = (const int*)d_in[1];
  const float* W1l = (const float*)d_in[2];
  const float* b1  = (const float*)d_in[3];
  const float* W1r = (const float*)d_in[4];
  const float* W2l = (const float*)d_in[5];
  const float* b2  = (const float*)d_in[6];
  const float* W2r = (const float*)d_in[7];
  float* out = (float*)d_out;

  const int* src = ei;            // edge_index[0]
  const int* dst = ei + N_EDGES;  // edge_index[1]

  const size_t F32 = (size_t)N_NODES * 32;
  char* w = (char*)d_ws;
  // region 1 (12.8 MB): bufA (binning) -> xr (transform/gather1) -> aggh (gather2/out2)
  unsigned* bufA = (unsigned*)w;                 // 49*34816*4 = 6.8 MB
  float* xr      = (float*)w;                    // 12.8 MB (bufA dead by then)
  float* aggh    = (float*)w;                    // 12.8 MB (xr dead after gather1)
  w += F32 * sizeof(float);
  // region 2 (12.8 MB): buf (binning) -> xlbh[2] + hpbh[2] half-tables
  unsigned* buf  = (unsigned*)w;                 // 3125*704*4 = 8.8 MB
  unsigned short* xlbh = (unsigned short*)w;     // 2 x 3.2 MB
  unsigned short* hpbh = xlbh + 2 * (size_t)N16; // 2 x 3.2 MB (buf dead by then)
  w += F32 * 2 * sizeof(unsigned short);
  int* curA  = (int*)w; w += NCC * sizeof(int);
  int* cur   = (int*)w; w += NB * sizeof(int);
  int* bbase = (int*)w; w += NB * sizeof(int);
  int* deg   = (int*)w; w += N_NODES * sizeof(int);
  int* offs  = (int*)w; w += N_NODES * sizeof(int);
  int* eidx  = (int*)w; w += (size_t)N_EDGES * sizeof(int);   // 6.4 MB (dense)
  unsigned long long* msk = (unsigned long long*)w;           // 1.2 MB masks

  hipMemsetAsync(curA, 0, (size_t)(NCC + NB) * sizeof(int), stream);

  k_mask<<<2048, 256, 0, stream>>>(msk);
  k_binA<<<(N_EDGES + 2047) / 2048, 256, 0, stream>>>(src, dst, curA, bufA);
  k_binB<<<NCC * BPC, 256, 0, stream>>>(bufA, curA, cur, buf);
  k_bscan<<<1, 1024, 0, stream>>>(cur, bbase);
  k_bfill<<<NB, 256, 0, stream>>>(buf, cur, bbase, deg, offs, eidx);

  k_transform1<<<1024, 256, 0, stream>>>(x, W1l, W1r, xlbh, xr);
  k_gather1<<<2 * GHB, 256, 0, stream>>>(xlbh, xr, offs, deg, eidx, b1, msk, hpbh);
  k_gather2<<<2 * GHB, 256, 0, stream>>>(hpbh, offs, deg, eidx, aggh);
  k_out2<<<1024, 256, 0, stream>>>(hpbh, aggh, W2l, b2, W2r, msk + M1W, out);
}